// Round 6
// baseline (206.531 us; speedup 1.0000x reference)
//
#include <hip/hip_runtime.h>
#include <hip/hip_bf16.h>

#define LSEQ 512
#define BATCH 256
#define DIM 256
#define WMAX 128
#define ROW4 (BATCH * DIM / 4)   // feats row stride in float4 units
#define BD4 (DIM / 4)            // batch stride in float4 units
#define MSTRIDE (WMAX + 2)       // meta ints per batch in ws
#define WPW 8                    // words per wave

// Kernel 1: one block per batch. Run-start positions via boundary detect
// (ids sorted+densified). Also writes the masks output.
__global__ __launch_bounds__(256) void meta_kernel(
    const int* __restrict__ word_ids,    // [B, L]
    const int* __restrict__ amask,       // [B, L]
    int* __restrict__ meta,              // [B, MSTRIDE]
    float* __restrict__ out)             // masks at offset W*B*D
{
    const int b = blockIdx.x;
    const int t = threadIdx.x;
    const int lane = t & 63;
    const int wi = t >> 6;

    __shared__ int sids[LSEQ];
    __shared__ int spart[4];
    __shared__ int sstart[WMAX + 1];

    int msum = 0;
    if (t < 128) {
        ((int4*)sids)[t] = ((const int4*)(word_ids + b * LSEQ))[t];
    } else {
        int4 m = ((const int4*)(amask + b * LSEQ))[t - 128];
        msum = m.x + m.y + m.z + m.w;
    }
    #pragma unroll
    for (int off = 32; off; off >>= 1) msum += __shfl_down(msum, off, 64);
    if (lane == 0) spart[wi] = msum;
    __syncthreads();

    const int char_num = spart[0] + spart[1] + spart[2] + spart[3] - 2;
    int pend = 1 + char_num;             // valid positions: [1, pend)
    if (pend < 1) pend = 1;
    if (pend > LSEQ) pend = LSEQ;

    if (t <= WMAX) sstart[t] = pend;     // sentinel: empty/tail words
    __syncthreads();

    for (int p = 1 + t; p < pend; p += 256) {
        if (p == 1 || sids[p] != sids[p - 1]) sstart[sids[p]] = p;
    }
    if (t == 0) sstart[0] = 1;
    __syncthreads();

    if (t <= WMAX) meta[b * MSTRIDE + t] = sstart[t];

    if (t < WMAX) {
        int word_num = sids[LSEQ - 1] + 1;   // sorted -> last element is max
        out[(size_t)WMAX * BATCH * DIM + (size_t)t * BATCH + b] =
            (t < word_num) ? 1.0f : 0.0f;
    }
}

// Kernel 2: one wave per (batch, 8 consecutive words). The wave's row range
// [sstart[w0], sstart[w0+8]) is CONTIGUOUS; it streams it with an 8-deep
// register double-buffer (next chunk's loads in flight while current folds).
// Flush logic is wave-uniform (b and boundaries are wave-scalar).
// Grid: 4*BATCH blocks of 256 threads (4 waves); wave (blockIdx>>8, wi)
// owns words [ (4*(blockIdx>>8)+wi)*8 , +8 ) of batch b = blockIdx&255.
__global__ __launch_bounds__(256, 4) void pool_kernel(
    const float* __restrict__ feats,     // [L, B, D]
    const int* __restrict__ meta,        // [B, MSTRIDE]
    float* __restrict__ out)             // [W, B, D]
{
    const int b = blockIdx.x & (BATCH - 1);
    const int wcg = blockIdx.x >> 8;         // 0..3
    const int t = threadIdx.x;
    const int lane = t & 63;
    const int wi = t >> 6;
    const int w0 = (wcg * 4 + wi) * WPW;     // first word of this wave

    // Boundaries sstart[w0..w0+8] -> scalar loads (uniform address).
    const int* mb = meta + __builtin_amdgcn_readfirstlane(b * MSTRIDE + w0);
    int bnd[WPW + 1];
    #pragma unroll
    for (int i = 0; i <= WPW; i++) bnd[i] = mb[i];

    const float4* __restrict__ f4 = (const float4*)feats;
    float4* __restrict__ o4 = (float4*)out;
    const int boff = b * BD4 + lane;

    const int R0 = bnd[0];
    const int R1 = bnd[WPW];                 // rows [R0, R1) feed these words

    float4 acc = make_float4(0.f, 0.f, 0.f, 0.f);
    int cur = 0;                             // word in progress (0..WPW-1)
    int nxt = bnd[1];

    if (R0 < R1) {
        int p = R0;
        float4 A[8], Bv[8];
        #pragma unroll
        for (int j = 0; j < 8; j++) {
            int r = p + j;
            A[j] = f4[(size_t)(r < R1 ? r : R1 - 1) * ROW4 + boff];
        }
        while (p < R1) {
            #pragma unroll
            for (int j = 0; j < 8; j++) {
                int r = p + 8 + j;
                Bv[j] = f4[(size_t)(r < R1 ? r : R1 - 1) * ROW4 + boff];
            }
            int n = R1 - p; if (n > 8) n = 8;
            #pragma unroll
            for (int j = 0; j < 8; j++) {
                if (j < n) {
                    const int pp = p + j;
                    while (pp >= nxt) {      // flush words ending before pp
                        const int c = nxt - bnd[cur];
                        const float inv = 1.0f / (float)(c > 0 ? c : 1);
                        o4[(size_t)(w0 + cur) * ROW4 + boff] = make_float4(
                            acc.x * inv, acc.y * inv, acc.z * inv, acc.w * inv);
                        acc = make_float4(0.f, 0.f, 0.f, 0.f);
                        cur++;
                        nxt = bnd[cur + 1];
                    }
                    acc.x += A[j].x; acc.y += A[j].y;
                    acc.z += A[j].z; acc.w += A[j].w;
                }
            }
            #pragma unroll
            for (int j = 0; j < 8; j++) A[j] = Bv[j];
            p += 8;
        }
    }

    // Epilogue: flush word in progress + trailing empty words.
    while (cur < WPW) {
        const int c = bnd[cur + 1] - bnd[cur];
        const float inv = 1.0f / (float)(c > 0 ? c : 1);
        o4[(size_t)(w0 + cur) * ROW4 + boff] = make_float4(
            acc.x * inv, acc.y * inv, acc.z * inv, acc.w * inv);
        acc = make_float4(0.f, 0.f, 0.f, 0.f);
        cur++;
    }
}

extern "C" void kernel_launch(void* const* d_in, const int* in_sizes, int n_in,
                              void* d_out, int out_size, void* d_ws, size_t ws_size,
                              hipStream_t stream) {
    const float* char_feats = (const float*)d_in[0];
    const int* word_ids     = (const int*)d_in[1];
    const int* amask        = (const int*)d_in[2];
    float* out              = (float*)d_out;
    int* meta               = (int*)d_ws;

    meta_kernel<<<BATCH, 256, 0, stream>>>(word_ids, amask, meta, out);
    pool_kernel<<<BATCH * 4, 256, 0, stream>>>(char_feats, meta, out);
}